// Round 1
// baseline (12570.646 us; speedup 1.0000x reference)
//
#include <hip/hip_runtime.h>
#include <hip/hip_bf16.h>
#include <stdint.h>

typedef __attribute__((ext_vector_type(8))) short bf16x8;
typedef __attribute__((ext_vector_type(4))) float f32x4;

#define NB   16
#define SEQ  512
#define DM   256
#define G4   1024
#define VOC  32000
#define TOK  (NB*SEQ)          // 8192 tokens

// ---------------- workspace layout (bytes) ----------------
#define OF_SC     0                                  // float[8]: 0 emb,1 wih0,2 whh0,3 wih1,4 whh1,5 fc,6 = 1.0f
#define OF_AMAX   64                                 // uint[8]
#define OF_KEMB   1024                               // bf16 int [8192,256]
#define OF_KWIH0  (OF_KEMB  + TOK*DM*2)              // bf16 int [1024,256]
#define OF_W0     (OF_KWIH0 + G4*DM*2)               // f32 q, packed-T [64][1024] float4  (whh0)
#define OF_W1I    (OF_W0    + G4*DM*4)               // wih1
#define OF_W1H    (OF_W1I   + G4*DM*4)               // whh1
#define OF_KFC    (OF_W1H   + G4*DM*4)               // bf16 int [32000,256]
#define OF_XG     (OF_KFC   + VOC*DM*2)              // f32 [8192,1024] pre-biased input gates
#define OF_HOUT   (OF_XG    + TOK*G4*4)              // bf16 [8192,256] lstm output
// total ~62 MB

__device__ __forceinline__ unsigned short bf16b(float f) {
  __hip_bfloat16 h = __float2bfloat16(f);
  return *reinterpret_cast<unsigned short*>(&h);
}
__device__ __forceinline__ float quant_k_val(float w, float s) {
  float k = rintf(w / s);                       // round-half-even == jnp.round
  return fminf(fmaxf(k, -8.f), 7.f);
}
__device__ __forceinline__ float sigf(float x) { return 1.f / (1.f + expf(-x)); }

__device__ __forceinline__ void gload_lds16(const void* g, void* l) {
  __builtin_amdgcn_global_load_lds(
      (const __attribute__((address_space(1))) void*)g,
      (__attribute__((address_space(3))) void*)l, 16, 0, 0);
}

// ---------------- scale computation ----------------
__global__ void k_init(unsigned int* amax) {
  if (threadIdx.x < 8) amax[threadIdx.x] = 0u;
}

__global__ void k_absmax(const float* __restrict__ p, int n, unsigned int* amax) {
  float m = 0.f;
  for (int i = blockIdx.x * blockDim.x + threadIdx.x; i < n; i += gridDim.x * blockDim.x)
    m = fmaxf(m, fabsf(p[i]));
  #pragma unroll
  for (int off = 32; off > 0; off >>= 1)
    m = fmaxf(m, __shfl_down(m, off));
  if ((threadIdx.x & 63) == 0) atomicMax(amax, __float_as_uint(m));  // bits of |f| order like floats
}

__global__ void k_finalize(const unsigned int* __restrict__ amax, float* __restrict__ sc) {
  int i = threadIdx.x;
  if (i < 6)       sc[i] = fmaxf(__uint_as_float(amax[i]) / 7.0f, 1e-8f);
  else if (i == 6) sc[i] = 1.0f;   // neutral scale for FC gemm's s2
}

// ---------------- quantize kernels ----------------
// integer code k in [-8,7] stored as bf16 (exact)
__global__ void k_quant_kbf16(const float* __restrict__ src, ushort* __restrict__ dst,
                              int n4, const float* __restrict__ sc, int slot) {
  int i = blockIdx.x * blockDim.x + threadIdx.x;
  if (i >= n4) return;
  const float s = sc[slot];
  float4 w = ((const float4*)src)[i];
  ushort4 o;
  o.x = bf16b(quant_k_val(w.x, s));
  o.y = bf16b(quant_k_val(w.y, s));
  o.z = bf16b(quant_k_val(w.z, s));
  o.w = bf16b(quant_k_val(w.w, s));
  ((ushort4*)dst)[i] = o;
}

// q = k*s in f32, packed-transposed: dst[k4][j] = float4(W[j][4k4..4k4+3]); j<1024, k4<64
__global__ void k_quant_qpack(const float* __restrict__ src, float4* __restrict__ dst,
                              const float* __restrict__ sc, int slot) {
  int i = blockIdx.x * blockDim.x + threadIdx.x;       // i = k4*1024 + j
  if (i >= 64 * G4) return;
  int k4 = i >> 10, j = i & 1023;
  const float s = sc[slot];
  float4 w = *(const float4*)(src + (size_t)j * DM + k4 * 4);
  float4 q;
  q.x = quant_k_val(w.x, s) * s;
  q.y = quant_k_val(w.y, s) * s;
  q.z = quant_k_val(w.z, s) * s;
  q.w = quant_k_val(w.w, s) * s;
  dst[i] = q;
}

// embedding gather + quantize to integer bf16 codes
__global__ void k_gather(const int* __restrict__ x, const float* __restrict__ emb,
                         const float* __restrict__ sc, ushort* __restrict__ out) {
  int i = blockIdx.x * blockDim.x + threadIdx.x;       // over TOK*64 float4 groups
  if (i >= TOK * 64) return;
  int tok = i >> 6, d4 = i & 63;
  const float s = sc[0];
  int row = x[tok];
  float4 w = *(const float4*)(emb + (size_t)row * DM + d4 * 4);
  ushort4 o;
  o.x = bf16b(quant_k_val(w.x, s));
  o.y = bf16b(quant_k_val(w.y, s));
  o.z = bf16b(quant_k_val(w.z, s));
  o.w = bf16b(quant_k_val(w.w, s));
  ((ushort4*)out)[i] = o;
}

// ---------------- 128x128 MFMA bf16 GEMM, C = alpha*(A@B^T) + bias1 + bias2 ----------------
// A [M,K] bf16 row-major, B [N,K] bf16 row-major, K == 256. M%128==0, N%128==0.
__global__ __launch_bounds__(256) void k_gemm(
    const ushort* __restrict__ A, const ushort* __restrict__ B,
    float* __restrict__ C, int M, int N,
    const float* __restrict__ s1, const float* __restrict__ s2,
    const float* __restrict__ bias1, const float* __restrict__ bias2)
{
  __shared__ alignas(16) ushort As[128 * 64];   // [128 rows][64 k] bf16
  __shared__ alignas(16) ushort Bs[128 * 64];
  const int tid  = threadIdx.x;
  const int lane = tid & 63;
  const int wid  = tid >> 6;
  const size_t m0 = (size_t)blockIdx.x * 128;
  const size_t n0 = (size_t)blockIdx.y * 128;
  const int wm = (wid >> 1) * 64;               // wave 2x2 grid over 128x128
  const int wn = (wid & 1) * 64;
  const int r  = tid >> 3;                      // staging: row-in-group 0..31
  const int c8 = (tid & 7) * 8;                 // staging: bf16 col offset

  f32x4 acc[4][4];
  #pragma unroll
  for (int m = 0; m < 4; ++m)
    #pragma unroll
    for (int n = 0; n < 4; ++n) acc[m][n] = (f32x4){0.f, 0.f, 0.f, 0.f};

  for (int k0 = 0; k0 < DM; k0 += 64) {
    #pragma unroll
    for (int i = 0; i < 4; ++i) {   // LDS dest = wave-uniform base; HW adds lane*16
      gload_lds16(A + (m0 + i * 32 + r) * DM + k0 + c8, (char*)As + i * 4096 + wid * 1024);
      gload_lds16(B + (n0 + i * 32 + r) * DM + k0 + c8, (char*)Bs + i * 4096 + wid * 1024);
    }
    __syncthreads();
    #pragma unroll
    for (int kk = 0; kk < 2; ++kk) {
      const int ko = (kk * 32 + ((lane >> 4) << 3)) * 2;  // byte offset of 8-bf16 chunk
      bf16x8 af[4], bfr[4];
      #pragma unroll
      for (int m = 0; m < 4; ++m)
        af[m] = *(const bf16x8*)((const char*)As + (wm + m * 16 + (lane & 15)) * 128 + ko);
      #pragma unroll
      for (int n = 0; n < 4; ++n)
        bfr[n] = *(const bf16x8*)((const char*)Bs + (wn + n * 16 + (lane & 15)) * 128 + ko);
      #pragma unroll
      for (int m = 0; m < 4; ++m)
        #pragma unroll
        for (int n = 0; n < 4; ++n)
          acc[m][n] = __builtin_amdgcn_mfma_f32_16x16x32_bf16(af[m], bfr[n], acc[m][n], 0, 0, 0);
    }
    __syncthreads();
  }

  const float alpha = s1[0] * s2[0];
  const int cl = lane & 15;
  const int rq = (lane >> 4) * 4;               // C/D: col=lane&15, row=(lane>>4)*4+q (m89-verified)
  #pragma unroll
  for (int n = 0; n < 4; ++n) {
    const size_t col = n0 + wn + n * 16 + cl;
    float badd = 0.f;
    if (bias1) badd += bias1[col];
    if (bias2) badd += bias2[col];
    #pragma unroll
    for (int m = 0; m < 4; ++m) {
      const size_t rowb = m0 + wm + m * 16 + rq;
      #pragma unroll
      for (int q = 0; q < 4; ++q)
        C[(rowb + q) * (size_t)N + col] = acc[m][n][q] * alpha + badd;
    }
  }
}

// ---------------- LSTM recurrence: one block per batch element ----------------
// xg: [16,512,1024] pre-biased input gates (layer0). Weights packed-T [64][1024] float4.
__global__ __launch_bounds__(1024) void k_lstm(
    const float* __restrict__ xg, const float4* __restrict__ W0,
    const float4* __restrict__ W1I, const float4* __restrict__ W1H,
    const float* __restrict__ bi1, const float* __restrict__ bh1,
    ushort* __restrict__ hout)
{
  __shared__ float h0s[DM], h1s[DM];
  __shared__ float gs[G4];
  const int j = threadIdx.x;                    // gate column 0..1023
  const int b = blockIdx.x;
  if (j < DM) { h0s[j] = 0.f; h1s[j] = 0.f; }
  float c0 = 0.f, c1 = 0.f;
  const float bias1 = bi1[j] + bh1[j];
  __syncthreads();
  const float4* h04 = (const float4*)h0s;
  const float4* h14 = (const float4*)h1s;

  for (int t = 0; t < SEQ; ++t) {
    const size_t tok = (size_t)b * SEQ + t;
    // ---- layer 0: gate j = xg + whh0[j,:] . h0 ----
    float acc = xg[tok * G4 + j];
    #pragma unroll 8
    for (int k = 0; k < 64; ++k) {
      float4 w = W0[k * G4 + j];                // coalesced: lane-consecutive float4
      float4 h = h04[k];                        // LDS broadcast
      acc += w.x * h.x + w.y * h.y + w.z * h.z + w.w * h.w;
    }
    gs[j] = acc;
    __syncthreads();
    if (j < DM) {
      float i_ = sigf(gs[j]);
      float f_ = sigf(gs[j + DM]);
      float g_ = tanhf(gs[j + 2 * DM]);
      float o_ = sigf(gs[j + 3 * DM]);
      c0 = f_ * c0 + i_ * g_;
      h0s[j] = o_ * tanhf(c0);
    }
    __syncthreads();
    // ---- layer 1: gate j = b + wih1[j,:] . h0new + whh1[j,:] . h1old ----
    float acc1 = bias1;
    #pragma unroll 4
    for (int k = 0; k < 64; ++k) {
      float4 w = W1I[k * G4 + j];
      float4 h = h04[k];
      acc1 += w.x * h.x + w.y * h.y + w.z * h.z + w.w * h.w;
    }
    #pragma unroll 4
    for (int k = 0; k < 64; ++k) {
      float4 w = W1H[k * G4 + j];
      float4 h = h14[k];
      acc1 += w.x * h.x + w.y * h.y + w.z * h.z + w.w * h.w;
    }
    gs[j] = acc1;
    __syncthreads();
    if (j < DM) {
      float i_ = sigf(gs[j]);
      float f_ = sigf(gs[j + DM]);
      float g_ = tanhf(gs[j + 2 * DM]);
      float o_ = sigf(gs[j + 3 * DM]);
      c1 = f_ * c1 + i_ * g_;
      float h = o_ * tanhf(c1);
      h1s[j] = h;
      __hip_bfloat16 hb = __float2bfloat16(h);
      hout[tok * DM + j] = *reinterpret_cast<unsigned short*>(&hb);
    }
    __syncthreads();
  }
}

// ---------------- launch ----------------
extern "C" void kernel_launch(void* const* d_in, const int* in_sizes, int n_in,
                              void* d_out, int out_size, void* d_ws, size_t ws_size,
                              hipStream_t stream) {
  const int*   x   = (const int*)d_in[0];
  const float* emb = (const float*)d_in[1];
  const float* wih = (const float*)d_in[2];   // [2,1024,256]
  const float* bih = (const float*)d_in[3];   // [2,1024]
  const float* whh = (const float*)d_in[4];
  const float* bhh = (const float*)d_in[5];
  const float* fcw = (const float*)d_in[6];   // [32000,256]
  const float* fcb = (const float*)d_in[7];
  float* out = (float*)d_out;

  char* ws = (char*)d_ws;
  float*        SC    = (float*)(ws + OF_SC);
  unsigned int* AMAX  = (unsigned int*)(ws + OF_AMAX);
  ushort*       KEMB  = (ushort*)(ws + OF_KEMB);
  ushort*       KWIH0 = (ushort*)(ws + OF_KWIH0);
  float4*       W0    = (float4*)(ws + OF_W0);
  float4*       W1I   = (float4*)(ws + OF_W1I);
  float4*       W1H   = (float4*)(ws + OF_W1H);
  ushort*       KFC   = (ushort*)(ws + OF_KFC);
  float*        XG    = (float*)(ws + OF_XG);
  ushort*       HOUT  = (ushort*)(ws + OF_HOUT);

  const int nw = G4 * DM;   // 262144 elements per LSTM weight matrix

  k_init<<<1, 64, 0, stream>>>(AMAX);
  k_absmax<<<2048, 256, 0, stream>>>(emb,      VOC * DM, AMAX + 0);
  k_absmax<<<256,  256, 0, stream>>>(wih,      nw,       AMAX + 1);
  k_absmax<<<256,  256, 0, stream>>>(whh,      nw,       AMAX + 2);
  k_absmax<<<256,  256, 0, stream>>>(wih + nw, nw,       AMAX + 3);
  k_absmax<<<256,  256, 0, stream>>>(whh + nw, nw,       AMAX + 4);
  k_absmax<<<2048, 256, 0, stream>>>(fcw,      VOC * DM, AMAX + 5);
  k_finalize<<<1, 8, 0, stream>>>(AMAX, SC);

  k_gather<<<TOK * 64 / 256, 256, 0, stream>>>(x, emb, SC, KEMB);
  k_quant_kbf16<<<nw / 4 / 256,       256, 0, stream>>>(wih, KWIH0, nw / 4,       SC, 1);
  k_quant_kbf16<<<VOC * DM / 4 / 256, 256, 0, stream>>>(fcw, KFC,   VOC * DM / 4, SC, 5);
  k_quant_qpack<<<64 * G4 / 256, 256, 0, stream>>>(whh,      W0,  SC, 2);
  k_quant_qpack<<<64 * G4 / 256, 256, 0, stream>>>(wih + nw, W1I, SC, 3);
  k_quant_qpack<<<64 * G4 / 256, 256, 0, stream>>>(whh + nw, W1H, SC, 4);

  // xgates = s_emb*s_wih0 * (k_emb @ k_wih0^T) + b_ih0 + b_hh0   (integer-exact MFMA)
  dim3 g1(TOK / 128, G4 / 128);
  k_gemm<<<g1, 256, 0, stream>>>(KEMB, KWIH0, XG, TOK, G4, SC + 0, SC + 1, bih, bhh);

  k_lstm<<<NB, 1024, 0, stream>>>(XG, W0, W1I, W1H, bih + G4, bhh + G4, HOUT);

  // logits = s_fc * (h @ k_fc^T) + fc_b
  dim3 g2(TOK / 128, VOC / 128);
  k_gemm<<<g2, 256, 0, stream>>>(HOUT, KFC, out, TOK, VOC, SC + 5, SC + 6, fcb, nullptr);
}

// Round 2
// 4611.415 us; speedup vs baseline: 2.7260x; 2.7260x over previous
//
#include <hip/hip_runtime.h>
#include <hip/hip_bf16.h>
#include <stdint.h>

typedef __attribute__((ext_vector_type(8))) short bf16x8;
typedef __attribute__((ext_vector_type(4))) float f32x4;

#define NB   16
#define SEQ  512
#define DM   256
#define G4   1024
#define VOC  32000
#define TOK  (NB*SEQ)          // 8192 tokens

// ---------------- workspace layout (bytes) ----------------
#define OF_SC     0                                  // float[8]
#define OF_AMAX   64                                 // uint[8]
#define OF_FLAG   128                                // int[64] pipeline flags
#define OF_KEMB   1024                               // bf16 codes [8192,256]
#define OF_KWIH0  (OF_KEMB  + TOK*DM*2)              // bf16 codes [1024,256]
#define OF_KFC    (OF_KWIH0 + G4*DM*2)               // bf16 codes [32000,256]
#define OF_KW0T   (OF_KFC   + VOC*DM*2)              // bf16 codes whh0, [32 k8][1024 col] x8
#define OF_KW1IT  (OF_KW0T  + G4*DM*2)               // wih1 same layout
#define OF_KW1HT  (OF_KW1IT + G4*DM*2)               // whh1 same layout
#define OF_H0S    (OF_KW1HT + G4*DM*2)               // f32 [16][512][256] h0 stream (8MB)
#define OF_XG     (OF_H0S   + TOK*DM*4)              // f32 [8192,1024]; reused by P1 as xg1 stream
#define OF_HOUT   (OF_XG    + TOK*G4*4)              // bf16 [8192,256]
// total ~66 MB

__device__ __forceinline__ unsigned short bf16b(float f) {
  __hip_bfloat16 h = __float2bfloat16(f);
  return *reinterpret_cast<unsigned short*>(&h);
}
__device__ __forceinline__ float bf16f(short u) {
  return __uint_as_float(((unsigned)(unsigned short)u) << 16);
}
__device__ __forceinline__ float quant_k_val(float w, float s) {
  float k = rintf(w / s);                       // round-half-even == jnp.round
  return fminf(fmaxf(k, -8.f), 7.f);
}
__device__ __forceinline__ float sigf(float x) { return 1.f / (1.f + expf(-x)); }

__device__ __forceinline__ void gload_lds16(const void* g, void* l) {
  __builtin_amdgcn_global_load_lds(
      (const __attribute__((address_space(1))) void*)g,
      (__attribute__((address_space(3))) void*)l, 16, 0, 0);
}

// ---------------- scale computation ----------------
__global__ void k_init(unsigned int* amax, int* flags) {
  if (threadIdx.x < 8)  amax[threadIdx.x] = 0u;
  if (threadIdx.x < 64) flags[threadIdx.x] = 0;
}

__global__ void k_absmax(const float* __restrict__ p, int n, unsigned int* amax) {
  float m = 0.f;
  for (int i = blockIdx.x * blockDim.x + threadIdx.x; i < n; i += gridDim.x * blockDim.x)
    m = fmaxf(m, fabsf(p[i]));
  #pragma unroll
  for (int off = 32; off > 0; off >>= 1)
    m = fmaxf(m, __shfl_down(m, off));
  if ((threadIdx.x & 63) == 0) atomicMax(amax, __float_as_uint(m));
}

__global__ void k_finalize(const unsigned int* __restrict__ amax, float* __restrict__ sc) {
  int i = threadIdx.x;
  if (i < 6)       sc[i] = fmaxf(__uint_as_float(amax[i]) / 7.0f, 1e-8f);
  else if (i == 6) sc[i] = 1.0f;
}

// ---------------- quantize kernels ----------------
__global__ void k_quant_kbf16(const float* __restrict__ src, ushort* __restrict__ dst,
                              int n4, const float* __restrict__ sc, int slot) {
  int i = blockIdx.x * blockDim.x + threadIdx.x;
  if (i >= n4) return;
  const float s = sc[slot];
  float4 w = ((const float4*)src)[i];
  ushort4 o;
  o.x = bf16b(quant_k_val(w.x, s));
  o.y = bf16b(quant_k_val(w.y, s));
  o.z = bf16b(quant_k_val(w.z, s));
  o.w = bf16b(quant_k_val(w.w, s));
  ((ushort4*)dst)[i] = o;
}

// pack codes transposed for streaming: dst[k8*1024 + j] = bf16(k of W[j][8k8..8k8+8))
__global__ void k_quant_kT8(const float* __restrict__ src, bf16x8* __restrict__ dst,
                            const float* __restrict__ sc, int slot) {
  int i = blockIdx.x * blockDim.x + threadIdx.x;     // 32*1024
  if (i >= 32 * G4) return;
  int k8 = i >> 10, j = i & 1023;
  const float s = sc[slot];
  const float* p = src + (size_t)j * DM + k8 * 8;
  bf16x8 o;
  #pragma unroll
  for (int v = 0; v < 8; ++v) o[v] = (short)bf16b(quant_k_val(p[v], s));
  dst[i] = o;
}

__global__ void k_gather(const int* __restrict__ x, const float* __restrict__ emb,
                         const float* __restrict__ sc, ushort* __restrict__ out) {
  int i = blockIdx.x * blockDim.x + threadIdx.x;
  if (i >= TOK * 64) return;
  int tok = i >> 6, d4 = i & 63;
  const float s = sc[0];
  int row = x[tok];
  float4 w = *(const float4*)(emb + (size_t)row * DM + d4 * 4);
  ushort4 o;
  o.x = bf16b(quant_k_val(w.x, s));
  o.y = bf16b(quant_k_val(w.y, s));
  o.z = bf16b(quant_k_val(w.z, s));
  o.w = bf16b(quant_k_val(w.w, s));
  ((ushort4*)out)[i] = o;
}

// ---------------- 128x128 MFMA bf16 GEMM (unchanged from R1) ----------------
__global__ __launch_bounds__(256) void k_gemm(
    const ushort* __restrict__ A, const ushort* __restrict__ B,
    float* __restrict__ C, int M, int N,
    const float* __restrict__ s1, const float* __restrict__ s2,
    const float* __restrict__ bias1, const float* __restrict__ bias2)
{
  __shared__ alignas(16) ushort As[128 * 64];
  __shared__ alignas(16) ushort Bs[128 * 64];
  const int tid  = threadIdx.x;
  const int lane = tid & 63;
  const int wid  = tid >> 6;
  const size_t m0 = (size_t)blockIdx.x * 128;
  const size_t n0 = (size_t)blockIdx.y * 128;
  const int wm = (wid >> 1) * 64;
  const int wn = (wid & 1) * 64;
  const int r  = tid >> 3;
  const int c8 = (tid & 7) * 8;

  f32x4 acc[4][4];
  #pragma unroll
  for (int m = 0; m < 4; ++m)
    #pragma unroll
    for (int n = 0; n < 4; ++n) acc[m][n] = (f32x4){0.f, 0.f, 0.f, 0.f};

  for (int k0 = 0; k0 < DM; k0 += 64) {
    #pragma unroll
    for (int i = 0; i < 4; ++i) {
      gload_lds16(A + (m0 + i * 32 + r) * DM + k0 + c8, (char*)As + i * 4096 + wid * 1024);
      gload_lds16(B + (n0 + i * 32 + r) * DM + k0 + c8, (char*)Bs + i * 4096 + wid * 1024);
    }
    __syncthreads();
    #pragma unroll
    for (int kk = 0; kk < 2; ++kk) {
      const int ko = (kk * 32 + ((lane >> 4) << 3)) * 2;
      bf16x8 af[4], bfr[4];
      #pragma unroll
      for (int m = 0; m < 4; ++m)
        af[m] = *(const bf16x8*)((const char*)As + (wm + m * 16 + (lane & 15)) * 128 + ko);
      #pragma unroll
      for (int n = 0; n < 4; ++n)
        bfr[n] = *(const bf16x8*)((const char*)Bs + (wn + n * 16 + (lane & 15)) * 128 + ko);
      #pragma unroll
      for (int m = 0; m < 4; ++m)
        #pragma unroll
        for (int n = 0; n < 4; ++n)
          acc[m][n] = __builtin_amdgcn_mfma_f32_16x16x32_bf16(af[m], bfr[n], acc[m][n], 0, 0, 0);
    }
    __syncthreads();
  }

  const float alpha = s1[0] * s2[0];
  const int cl = lane & 15;
  const int rq = (lane >> 4) * 4;
  #pragma unroll
  for (int n = 0; n < 4; ++n) {
    const size_t col = n0 + wn + n * 16 + cl;
    float badd = 0.f;
    if (bias1) badd += bias1[col];
    if (bias2) badd += bias2[col];
    #pragma unroll
    for (int m = 0; m < 4; ++m) {
      const size_t rowb = m0 + wm + m * 16 + rq;
      #pragma unroll
      for (int q = 0; q < 4; ++q)
        C[(rowb + q) * (size_t)N + col] = acc[m][n][q] * alpha + badd;
    }
  }
}

// ---------------- 3-stage layer-skew LSTM pipeline ----------------
// grid = 48 blocks x 1024 threads. block = (stage<<4)|batch.
//  stage 0: h0 recurrence (whh0 codes)     -> H0S stream, flag F0[b]
//  stage 1: xg1 = bias1 + s3*(wih1 . h0)   -> XG (reused) stream, flag F1[b]
//  stage 2: h1 recurrence (whh1 codes)     -> HOUT bf16
// Flags zeroed by k_init each launch. 48 blocks always co-resident (<=256 CUs),
// consumers only wait on producers => acyclic, no deadlock.
__global__ __launch_bounds__(1024) void k_pipe(
    const bf16x8* __restrict__ KW0T, const bf16x8* __restrict__ KW1IT,
    const bf16x8* __restrict__ KW1HT, const float* __restrict__ sc,
    const float* __restrict__ bi1, const float* __restrict__ bh1,
    float* __restrict__ xg, float* __restrict__ H0S,
    ushort* __restrict__ hout, int* __restrict__ flags)
{
  __shared__ float hs[DM];
  __shared__ float gs[G4];
  const int j = threadIdx.x;
  const int b = blockIdx.x & 15;
  const int stage = blockIdx.x >> 4;
  int* F0 = flags;        // [16]
  int* F1 = flags + 16;   // [16]

  if (stage == 0) {
    // ---- layer-0 recurrence ----
    if (j < DM) hs[j] = 0.f;
    float c0 = 0.f;
    const float s2 = sc[2];
    __syncthreads();
    for (int t = 0; t < SEQ; ++t) {
      const size_t tok = (size_t)b * SEQ + t;
      float dot = 0.f;
      const float4* h4 = (const float4*)hs;
      #pragma unroll 8
      for (int k8 = 0; k8 < 32; ++k8) {
        bf16x8 w = KW0T[(k8 << 10) + j];
        float4 ha = h4[k8 * 2], hb = h4[k8 * 2 + 1];
        dot += bf16f(w[0]) * ha.x + bf16f(w[1]) * ha.y + bf16f(w[2]) * ha.z + bf16f(w[3]) * ha.w
             + bf16f(w[4]) * hb.x + bf16f(w[5]) * hb.y + bf16f(w[6]) * hb.z + bf16f(w[7]) * hb.w;
      }
      float g = xg[tok * G4 + j] + s2 * dot;
      gs[j] = g;
      __syncthreads();
      if (j < DM) {
        float i_ = sigf(gs[j]);
        float f_ = sigf(gs[j + DM]);
        float g_ = tanhf(gs[j + 2 * DM]);
        float o_ = sigf(gs[j + 3 * DM]);
        c0 = f_ * c0 + i_ * g_;
        float h = o_ * tanhf(c0);
        hs[j] = h;
        H0S[tok * DM + j] = h;
      }
      __syncthreads();   // drains vmcnt: H0S stores globally issued before flag
      if (j == 0)
        __hip_atomic_store(&F0[b], t + 1, __ATOMIC_RELEASE, __HIP_MEMORY_SCOPE_AGENT);
    }
  } else if (stage == 1) {
    // ---- feed-forward xg1 = bias1 + s3 * (wih1 . h0[t]) ----
    const float s3 = sc[3];
    const float bias1 = bi1[j] + bh1[j];
    for (int t = 0; t < SEQ; ++t) {
      const size_t tok = (size_t)b * SEQ + t;
      if (j == 0) {
        int iters = 0;
        while (__hip_atomic_load(&F0[b], __ATOMIC_ACQUIRE, __HIP_MEMORY_SCOPE_AGENT) < t + 1) {
          __builtin_amdgcn_s_sleep(2);
          if (++iters > (1 << 17)) break;   // bailout: wrong answer beats hang
        }
      }
      __syncthreads();
      if (j < DM) hs[j] = H0S[tok * DM + j];
      __syncthreads();
      float dot = 0.f;
      const float4* h4 = (const float4*)hs;
      #pragma unroll 8
      for (int k8 = 0; k8 < 32; ++k8) {
        bf16x8 w = KW1IT[(k8 << 10) + j];
        float4 ha = h4[k8 * 2], hb = h4[k8 * 2 + 1];
        dot += bf16f(w[0]) * ha.x + bf16f(w[1]) * ha.y + bf16f(w[2]) * ha.z + bf16f(w[3]) * ha.w
             + bf16f(w[4]) * hb.x + bf16f(w[5]) * hb.y + bf16f(w[6]) * hb.z + bf16f(w[7]) * hb.w;
      }
      xg[tok * G4 + j] = bias1 + s3 * dot;  // safe reuse: P0 read xg[tok] before F0=t+1
      __syncthreads();   // drain store
      if (j == 0)
        __hip_atomic_store(&F1[b], t + 1, __ATOMIC_RELEASE, __HIP_MEMORY_SCOPE_AGENT);
    }
  } else {
    // ---- layer-1 recurrence ----
    if (j < DM) hs[j] = 0.f;
    float c1 = 0.f;
    const float s4 = sc[4];
    __syncthreads();
    for (int t = 0; t < SEQ; ++t) {
      const size_t tok = (size_t)b * SEQ + t;
      if (j == 0) {
        int iters = 0;
        while (__hip_atomic_load(&F1[b], __ATOMIC_ACQUIRE, __HIP_MEMORY_SCOPE_AGENT) < t + 1) {
          __builtin_amdgcn_s_sleep(2);
          if (++iters > (1 << 17)) break;
        }
      }
      __syncthreads();
      float xv = xg[tok * G4 + j];
      float dot = 0.f;
      const float4* h4 = (const float4*)hs;
      #pragma unroll 8
      for (int k8 = 0; k8 < 32; ++k8) {
        bf16x8 w = KW1HT[(k8 << 10) + j];
        float4 ha = h4[k8 * 2], hb = h4[k8 * 2 + 1];
        dot += bf16f(w[0]) * ha.x + bf16f(w[1]) * ha.y + bf16f(w[2]) * ha.z + bf16f(w[3]) * ha.w
             + bf16f(w[4]) * hb.x + bf16f(w[5]) * hb.y + bf16f(w[6]) * hb.z + bf16f(w[7]) * hb.w;
      }
      gs[j] = xv + s4 * dot;
      __syncthreads();
      if (j < DM) {
        float i_ = sigf(gs[j]);
        float f_ = sigf(gs[j + DM]);
        float g_ = tanhf(gs[j + 2 * DM]);
        float o_ = sigf(gs[j + 3 * DM]);
        c1 = f_ * c1 + i_ * g_;
        float h = o_ * tanhf(c1);
        hs[j] = h;
        __hip_bfloat16 hb16 = __float2bfloat16(h);
        hout[tok * DM + j] = *reinterpret_cast<unsigned short*>(&hb16);
      }
      __syncthreads();
    }
  }
}

// ---------------- launch ----------------
extern "C" void kernel_launch(void* const* d_in, const int* in_sizes, int n_in,
                              void* d_out, int out_size, void* d_ws, size_t ws_size,
                              hipStream_t stream) {
  const int*   x   = (const int*)d_in[0];
  const float* emb = (const float*)d_in[1];
  const float* wih = (const float*)d_in[2];   // [2,1024,256]
  const float* bih = (const float*)d_in[3];   // [2,1024]
  const float* whh = (const float*)d_in[4];
  const float* bhh = (const float*)d_in[5];
  const float* fcw = (const float*)d_in[6];   // [32000,256]
  const float* fcb = (const float*)d_in[7];
  float* out = (float*)d_out;

  char* ws = (char*)d_ws;
  float*        SC    = (float*)(ws + OF_SC);
  unsigned int* AMAX  = (unsigned int*)(ws + OF_AMAX);
  int*          FLAGS = (int*)(ws + OF_FLAG);
  ushort*       KEMB  = (ushort*)(ws + OF_KEMB);
  ushort*       KWIH0 = (ushort*)(ws + OF_KWIH0);
  ushort*       KFC   = (ushort*)(ws + OF_KFC);
  bf16x8*       KW0T  = (bf16x8*)(ws + OF_KW0T);
  bf16x8*       KW1IT = (bf16x8*)(ws + OF_KW1IT);
  bf16x8*       KW1HT = (bf16x8*)(ws + OF_KW1HT);
  float*        H0S   = (float*)(ws + OF_H0S);
  float*        XG    = (float*)(ws + OF_XG);
  ushort*       HOUT  = (ushort*)(ws + OF_HOUT);

  const int nw = G4 * DM;

  k_init<<<1, 64, 0, stream>>>(AMAX, FLAGS);
  k_absmax<<<2048, 256, 0, stream>>>(emb,      VOC * DM, AMAX + 0);
  k_absmax<<<256,  256, 0, stream>>>(wih,      nw,       AMAX + 1);
  k_absmax<<<256,  256, 0, stream>>>(whh,      nw,       AMAX + 2);
  k_absmax<<<256,  256, 0, stream>>>(wih + nw, nw,       AMAX + 3);
  k_absmax<<<256,  256, 0, stream>>>(whh + nw, nw,       AMAX + 4);
  k_absmax<<<2048, 256, 0, stream>>>(fcw,      VOC * DM, AMAX + 5);
  k_finalize<<<1, 8, 0, stream>>>(AMAX, SC);

  k_gather<<<TOK * 64 / 256, 256, 0, stream>>>(x, emb, SC, KEMB);
  k_quant_kbf16<<<nw / 4 / 256,       256, 0, stream>>>(wih, KWIH0, nw / 4,       SC, 1);
  k_quant_kbf16<<<VOC * DM / 4 / 256, 256, 0, stream>>>(fcw, KFC,   VOC * DM / 4, SC, 5);
  k_quant_kT8<<<32 * G4 / 256, 256, 0, stream>>>(whh,      KW0T,  SC, 2);
  k_quant_kT8<<<32 * G4 / 256, 256, 0, stream>>>(wih + nw, KW1IT, SC, 3);
  k_quant_kT8<<<32 * G4 / 256, 256, 0, stream>>>(whh + nw, KW1HT, SC, 4);

  // xgates(layer0) = s0*s1 * (k_emb @ k_wih0^T) + b_ih0 + b_hh0
  dim3 g1(TOK / 128, G4 / 128);
  k_gemm<<<g1, 256, 0, stream>>>(KEMB, KWIH0, XG, TOK, G4, SC + 0, SC + 1, bih, bhh);

  k_pipe<<<48, 1024, 0, stream>>>(KW0T, KW1IT, KW1HT, SC,
                                  bih + G4, bhh + G4, XG, H0S, HOUT, FLAGS);

  // logits = s_fc * (h @ k_fc^T) + fc_b
  dim3 g2(TOK / 128, VOC / 128);
  k_gemm<<<g2, 256, 0, stream>>>(HOUT, KFC, out, TOK, VOC, SC + 5, SC + 6, fcb, nullptr);
}